// Round 1
// baseline (496.377 us; speedup 1.0000x reference)
//
#include <hip/hip_runtime.h>
#include <stdint.h>

// BiMultiHeadAttention (GLIP bi-attention), MI355X bf16 MFMA pipeline.
// B=32 VN=576 LN=128 E=1024 H=16 D=64, V_DIM=1024 L_DIM=768, SCALE=0.25.

typedef unsigned short bfu;   // bf16 storage (avoid hip_bf16 API differences)
typedef __attribute__((ext_vector_type(4))) float f32x4;
typedef __attribute__((ext_vector_type(8))) short short8;
typedef __attribute__((ext_vector_type(4))) unsigned short u16x4;

#define MFMA16(a,b,c) __builtin_amdgcn_mfma_f32_16x16x32_bf16((a),(b),(c),0,0,0)
#define SCALE_QK 0.25f

__device__ __forceinline__ unsigned short f2bf(float x) {
  unsigned int u = __float_as_uint(x);
  u += 0x7fffu + ((u >> 16) & 1u);   // round-to-nearest-even
  return (unsigned short)(u >> 16);
}

__device__ __forceinline__ void gload_lds16(const void* g, void* l) {
  __builtin_amdgcn_global_load_lds(
      reinterpret_cast<__attribute__((address_space(1))) void*>(
          reinterpret_cast<uintptr_t>(g)),
      reinterpret_cast<__attribute__((address_space(3))) void*>(
          (uint32_t)reinterpret_cast<uintptr_t>(l)),
      16, 0, 0);
}

// ---------------------------------------------------------------- converts
__global__ void cvt_f32_bf16(const float* __restrict__ x, bfu* __restrict__ y, int n4) {
  for (int i = blockIdx.x * blockDim.x + threadIdx.x; i < n4; i += gridDim.x * blockDim.x) {
    const float4 f = *reinterpret_cast<const float4*>(x + (size_t)i * 4);
    u16x4 o;
    o[0] = f2bf(f.x); o[1] = f2bf(f.y); o[2] = f2bf(f.z); o[3] = f2bf(f.w);
    *reinterpret_cast<u16x4*>(y + (size_t)i * 4) = o;
  }
}

// ---------------------------------------------------------------- GEMM (C = A @ W^T + bias), m97 structure
// A: M x K bf16 row-major; W: N x K bf16 row-major. M%128==0, N%128==0, K%32==0.
__global__ __launch_bounds__(256) void gemm_bt(
    const bfu* __restrict__ A, const bfu* __restrict__ W, const float* __restrict__ bias,
    bfu* __restrict__ Cb, float* __restrict__ Cf,
    int M, int N, int K, int nbn)
{
  __shared__ bfu As[128 * 32];
  __shared__ bfu Bs[128 * 32];
  const int bid = blockIdx.x;
  const int bm = bid / nbn, bn = bid % nbn;
  const int t = threadIdx.x, l = t & 63, w = t >> 6;
  const int g = l >> 4, c = l & 15;
  const int wr = (w >> 1) * 64, wc = (w & 1) * 64;

  f32x4 zero = {0.f, 0.f, 0.f, 0.f};
  f32x4 acc[4][4];
  for (int m = 0; m < 4; ++m)
    for (int n = 0; n < 4; ++n) acc[m][n] = zero;

  const int rowA = l >> 2;          // 0..15 within 16-row chunk
  const int kb   = (l & 3) * 16;    // byte offset within 64B row

  for (int k0 = 0; k0 < K; k0 += 32) {
#pragma unroll
    for (int i = 0; i < 2; ++i) {
      int chunk = w * 2 + i;
      int r = chunk * 16 + rowA;
      const char* ga = (const char*)(A + (size_t)(bm * 128 + r) * K + k0) + kb;
      const char* gb = (const char*)(W + (size_t)(bn * 128 + r) * K + k0) + kb;
      gload_lds16(ga, (char*)As + chunk * 1024);
      gload_lds16(gb, (char*)Bs + chunk * 1024);
    }
    __syncthreads();
    short8 a[4], bf[4];
#pragma unroll
    for (int m = 0; m < 4; ++m)
      a[m] = *reinterpret_cast<const short8*>(&As[(wr + m * 16 + c) * 32 + g * 8]);
#pragma unroll
    for (int n = 0; n < 4; ++n)
      bf[n] = *reinterpret_cast<const short8*>(&Bs[(wc + n * 16 + c) * 32 + g * 8]);
#pragma unroll
    for (int m = 0; m < 4; ++m)
#pragma unroll
      for (int n = 0; n < 4; ++n)
        acc[m][n] = MFMA16(a[m], bf[n], acc[m][n]);
    __syncthreads();
  }

#pragma unroll
  for (int n = 0; n < 4; ++n) {
    int col = bn * 128 + wc + n * 16 + c;
    float bs = bias[col];
#pragma unroll
    for (int m = 0; m < 4; ++m) {
      int row0 = bm * 128 + wr + m * 16 + g * 4;
#pragma unroll
      for (int r = 0; r < 4; ++r) {
        float val = acc[m][n][r] + bs;
        size_t idx = (size_t)(row0 + r) * N + col;
        if (Cf) Cf[idx] = val;
        else    Cb[idx] = f2bf(val);
      }
    }
  }
}

// ---------------------------------------------------------------- transpose per (b,h): X[b, r, h*64+d] -> T[bh, d, r]
__global__ __launch_bounds__(256) void transpose_bh(
    const bfu* __restrict__ X, bfu* __restrict__ T, int R)
{
  __shared__ short tile[64][72];
  const int bh = blockIdx.x;
  const int b = bh >> 4, h = bh & 15;
  const int t = threadIdx.x;
  for (int q0 = 0; q0 < R; q0 += 64) {
    __syncthreads();
#pragma unroll
    for (int i = 0; i < 2; ++i) {
      int e = (t + i * 256) * 8;
      int r = e >> 6, d = e & 63;
      short8 v = *reinterpret_cast<const short8*>(X + ((size_t)(b * R + q0 + r) * 1024 + h * 64 + d));
#pragma unroll
      for (int j = 0; j < 8; ++j) tile[r][d + j] = v[j];
    }
    __syncthreads();
    int d = t >> 2, qo = (t & 3) * 16;
    short8 o0, o1;
#pragma unroll
    for (int j = 0; j < 8; ++j) o0[j] = tile[qo + j][d];
#pragma unroll
    for (int j = 0; j < 8; ++j) o1[j] = tile[qo + 8 + j][d];
    size_t base = ((size_t)bh * 64 + d) * R + q0 + qo;
    *reinterpret_cast<short8*>(T + base)     = o0;
    *reinterpret_cast<short8*>(T + base + 8) = o1;
  }
}

// ---------------------------------------------------------------- fused bidirectional attention per (b,h)
// Q: [B,576,16,64] (as 18432x1024), K: [B,128,16,64], LVt: [bh,64,128], VVt: [bh,64,576]
// xv[b,q,h,d] = sum_k exp(S[q,k]+m[k]) LV[k,d] / sum_k exp(S+m)    (row softmax)
// xl[b,k,h,d] = sum_q exp(S[q,k]) VV[q,d] / sum_q exp(S)           (col softmax)
// No max subtraction: |S*0.25| <~ 12 for this data; exp safe in f32.
__device__ __forceinline__ int pvt_off(int q, int kbyte) { return q * 256 + (kbyte ^ ((q & 7) << 4)); }
__device__ __forceinline__ int plt_off(int k, int qbyte) { return k * 64  + (qbyte ^ ((k & 3) << 4)); }

__global__ __launch_bounds__(512) void attn_fused(
    const bfu* __restrict__ Q, const bfu* __restrict__ Kl,
    const bfu* __restrict__ LVt, const bfu* __restrict__ VVt,
    const float* __restrict__ mask,
    bfu* __restrict__ xv, bfu* __restrict__ xl)
{
  __shared__ short PvT[8][2048];      // per-wave Pv tile 16x128 bf16, swizzled
  __shared__ short PlT[8][512];       // per-wave Pl^T tile 16x32 bf16, swizzled
  __shared__ float colpart[8][128];
  __shared__ float colinv[128];

  const int bh = blockIdx.x;
  const int b = bh >> 4, h = bh & 15;
  const int t = threadIdx.x, l = t & 63, w = t >> 6;
  const int g = l >> 4, c = l & 15;

  const bfu* Qb   = Q   + ((size_t)b * 576 * 1024 + h * 64);
  const bfu* Kb   = Kl  + ((size_t)b * 128 * 1024 + h * 64);
  const bfu* LVtb = LVt + (size_t)bh * 64 * 128;
  const bfu* VVtb = VVt + (size_t)bh * 64 * 576;

  const f32x4 zero = {0.f, 0.f, 0.f, 0.f};

  float em[8];
#pragma unroll
  for (int kt = 0; kt < 8; ++kt) em[kt] = __expf(mask[kt * 16 + c]);

  float colacc[8] = {0, 0, 0, 0, 0, 0, 0, 0};
  char* myPv = (char*)&PvT[w][0];

  // ---- Phase B1: waves own q-chunks (5,5,5,5,4,4,4,4 qtiles of 16)
  const int qt0 = (w < 4) ? w * 5 : 20 + (w - 4) * 4;
  const int nqt = (w < 4) ? 5 : 4;

  for (int iq = 0; iq < nqt; ++iq) {
    const int qt = qt0 + iq;
    f32x4 sacc[8];
#pragma unroll
    for (int kt = 0; kt < 8; ++kt) sacc[kt] = zero;
#pragma unroll
    for (int kk = 0; kk < 2; ++kk) {
      short8 aq = *reinterpret_cast<const short8*>(Qb + (size_t)(qt * 16 + c) * 1024 + kk * 32 + g * 8);
#pragma unroll
      for (int kt = 0; kt < 8; ++kt) {
        short8 bk = *reinterpret_cast<const short8*>(Kb + (size_t)(kt * 16 + c) * 1024 + kk * 32 + g * 8);
        sacc[kt] = MFMA16(aq, bk, sacc[kt]);
      }
    }
    // exp + stats + Pv tile write.  D layout: row(q) = g*4+r, col(k) = c (per ktile)
    float rs[4] = {0, 0, 0, 0};
#pragma unroll
    for (int kt = 0; kt < 8; ++kt) {
#pragma unroll
      for (int r = 0; r < 4; ++r) {
        float El = __expf(sacc[kt][r] * SCALE_QK);
        float Ev = El * em[kt];
        rs[r] += Ev;
        colacc[kt] += El;
        *reinterpret_cast<unsigned short*>(myPv + pvt_off(g * 4 + r, 2 * (kt * 16 + c))) = f2bf(Ev);
      }
    }
#pragma unroll
    for (int r = 0; r < 4; ++r) {
      rs[r] += __shfl_xor(rs[r], 1);
      rs[r] += __shfl_xor(rs[r], 2);
      rs[r] += __shfl_xor(rs[r], 4);
      rs[r] += __shfl_xor(rs[r], 8);
    }
    // xv tile = Pv(16x128) @ LV(128x64)
    short8 av[4];
#pragma unroll
    for (int kc = 0; kc < 4; ++kc)
      av[kc] = *reinterpret_cast<const short8*>(myPv + pvt_off(c, kc * 64 + g * 16));
    f32x4 oxv[4];
#pragma unroll
    for (int dt = 0; dt < 4; ++dt) oxv[dt] = zero;
#pragma unroll
    for (int dt = 0; dt < 4; ++dt)
#pragma unroll
      for (int kc = 0; kc < 4; ++kc) {
        short8 bv = *reinterpret_cast<const short8*>(LVtb + (size_t)(dt * 16 + c) * 128 + kc * 32 + g * 8);
        oxv[dt] = MFMA16(av[kc], bv, oxv[dt]);
      }
#pragma unroll
    for (int r = 0; r < 4; ++r) rs[r] = 1.0f / rs[r];
#pragma unroll
    for (int dt = 0; dt < 4; ++dt)
#pragma unroll
      for (int r = 0; r < 4; ++r) {
        float val = oxv[dt][r] * rs[r];
        xv[(size_t)(b * 576 + qt * 16 + g * 4 + r) * 1024 + h * 64 + dt * 16 + c] = f2bf(val);
      }
  }
  // cross-group then cross-wave colsum reduction
#pragma unroll
  for (int kt = 0; kt < 8; ++kt) {
    colacc[kt] += __shfl_xor(colacc[kt], 16);
    colacc[kt] += __shfl_xor(colacc[kt], 32);
  }
  if (g == 0) {
#pragma unroll
    for (int kt = 0; kt < 8; ++kt) colpart[w][kt * 16 + c] = colacc[kt];
  }
  __syncthreads();
  if (t < 128) {
    float s = 0.f;
#pragma unroll
    for (int ww = 0; ww < 8; ++ww) s += colpart[ww][t];
    colinv[t] = 1.0f / s;
  }
  __syncthreads();

  // ---- Phase B2: wave owns ktile w (16 lang positions); recompute S, xl = Pl^T @ VV
  short8 bkk[2];
#pragma unroll
  for (int kk = 0; kk < 2; ++kk)
    bkk[kk] = *reinterpret_cast<const short8*>(Kb + (size_t)(w * 16 + c) * 1024 + kk * 32 + g * 8);
  char* myPl = (char*)&PlT[w][0];
  f32x4 oxl[4];
#pragma unroll
  for (int dt = 0; dt < 4; ++dt) oxl[dt] = zero;

  for (int p = 0; p < 18; ++p) {
    f32x4 s0 = zero, s1 = zero;
#pragma unroll
    for (int kk = 0; kk < 2; ++kk) {
      short8 a0 = *reinterpret_cast<const short8*>(Qb + (size_t)((2 * p) * 16 + c) * 1024 + kk * 32 + g * 8);
      short8 a1 = *reinterpret_cast<const short8*>(Qb + (size_t)((2 * p + 1) * 16 + c) * 1024 + kk * 32 + g * 8);
      s0 = MFMA16(a0, bkk[kk], s0);
      s1 = MFMA16(a1, bkk[kk], s1);
    }
#pragma unroll
    for (int half = 0; half < 2; ++half) {
      f32x4 s = half ? s1 : s0;
      unsigned int w0 = (unsigned int)f2bf(__expf(s[0] * SCALE_QK)) |
                        ((unsigned int)f2bf(__expf(s[1] * SCALE_QK)) << 16);
      unsigned int w1 = (unsigned int)f2bf(__expf(s[2] * SCALE_QK)) |
                        ((unsigned int)f2bf(__expf(s[3] * SCALE_QK)) << 16);
      int qb = half * 32 + g * 8;
      *reinterpret_cast<unsigned int*>(myPl + plt_off(c, qb))     = w0;
      *reinterpret_cast<unsigned int*>(myPl + plt_off(c, qb + 4)) = w1;
    }
    short8 apl = *reinterpret_cast<const short8*>(myPl + plt_off(c, g * 16));
#pragma unroll
    for (int dt = 0; dt < 4; ++dt) {
      short8 bv = *reinterpret_cast<const short8*>(VVtb + (size_t)(dt * 16 + c) * 576 + p * 32 + g * 8);
      oxl[dt] = MFMA16(apl, bv, oxl[dt]);
    }
  }
  float ci[4];
#pragma unroll
  for (int r = 0; r < 4; ++r) ci[r] = colinv[w * 16 + g * 4 + r];
#pragma unroll
  for (int dt = 0; dt < 4; ++dt)
#pragma unroll
    for (int r = 0; r < 4; ++r) {
      float val = oxl[dt][r] * ci[r];
      xl[(size_t)(b * 128 + w * 16 + g * 4 + r) * 1024 + h * 64 + dt * 16 + c] = f2bf(val);
    }
}

// ---------------------------------------------------------------- host
static inline int cvt_grid(int n4) {
  int g = (n4 + 255) / 256;
  return g > 4096 ? 4096 : g;
}

extern "C" void kernel_launch(void* const* d_in, const int* in_sizes, int n_in,
                              void* d_out, int out_size, void* d_ws, size_t ws_size,
                              hipStream_t stream)
{
  const float* v    = (const float*)d_in[0];
  const float* lx   = (const float*)d_in[1];
  const float* mask = (const float*)d_in[2];
  const float* Wvq  = (const float*)d_in[3];
  const float* bvq  = (const float*)d_in[4];
  const float* Wlk  = (const float*)d_in[5];
  const float* blk  = (const float*)d_in[6];
  const float* Wvv  = (const float*)d_in[7];
  const float* bvv  = (const float*)d_in[8];
  const float* Wlv  = (const float*)d_in[9];
  const float* blv  = (const float*)d_in[10];
  const float* Wvo  = (const float*)d_in[11];
  const float* bvo  = (const float*)d_in[12];
  const float* Wlo  = (const float*)d_in[13];
  const float* blo  = (const float*)d_in[14];

  float* out_xv = (float*)d_out;                       // 18432 x 1024
  float* out_xl = out_xv + (size_t)18432 * 1024;       // 4096 x 768

  bfu* ws  = (bfu*)d_ws;
  bfu* vb  = ws;                      // 18874368 elems (aliased later as xv bf16)
  bfu* lb  = vb  + 18874368;          // 3145728
  bfu* wq  = lb  + 3145728;           // 1048576
  bfu* wk  = wq  + 1048576;           // 786432
  bfu* wv  = wk  + 786432;            // 1048576
  bfu* wlv = wv  + 1048576;           // 786432
  bfu* wvo = wlv + 786432;            // 1048576
  bfu* wlo = wvo + 1048576;           // 786432
  bfu* Qb  = wlo + 786432;            // 18874368
  bfu* VVb = Qb  + 18874368;          // 18874368
  bfu* Kb  = VVb + 18874368;          // 4194304
  bfu* LVb = Kb  + 4194304;           // 4194304 (aliased later as xl bf16)
  bfu* LVt = LVb + 4194304;           // 4194304
  bfu* VVt = LVt + 4194304;           // 18874368   total ~193 MB

  // 1) convert inputs + weights to bf16
  cvt_f32_bf16<<<cvt_grid(18874368 / 4), 256, 0, stream>>>(v,   vb,  18874368 / 4);
  cvt_f32_bf16<<<cvt_grid(3145728  / 4), 256, 0, stream>>>(lx,  lb,  3145728  / 4);
  cvt_f32_bf16<<<cvt_grid(1048576  / 4), 256, 0, stream>>>(Wvq, wq,  1048576  / 4);
  cvt_f32_bf16<<<cvt_grid(786432   / 4), 256, 0, stream>>>(Wlk, wk,  786432   / 4);
  cvt_f32_bf16<<<cvt_grid(1048576  / 4), 256, 0, stream>>>(Wvv, wv,  1048576  / 4);
  cvt_f32_bf16<<<cvt_grid(786432   / 4), 256, 0, stream>>>(Wlv, wlv, 786432   / 4);
  cvt_f32_bf16<<<cvt_grid(1048576  / 4), 256, 0, stream>>>(Wvo, wvo, 1048576  / 4);
  cvt_f32_bf16<<<cvt_grid(786432   / 4), 256, 0, stream>>>(Wlo, wlo, 786432   / 4);

  // 2) projection GEMMs (bf16 out)
  gemm_bt<<<144 * 8, 256, 0, stream>>>(vb, wq,  bvq, Qb,  nullptr, 18432, 1024, 1024, 8);
  gemm_bt<<<144 * 8, 256, 0, stream>>>(vb, wv,  bvv, VVb, nullptr, 18432, 1024, 1024, 8);
  gemm_bt<<<32 * 8,  256, 0, stream>>>(lb, wk,  blk, Kb,  nullptr, 4096,  1024, 768,  8);
  gemm_bt<<<32 * 8,  256, 0, stream>>>(lb, wlv, blv, LVb, nullptr, 4096,  1024, 768,  8);

  // 3) transposes for attention B-operands
  transpose_bh<<<512, 256, 0, stream>>>(LVb, LVt, 128);
  transpose_bh<<<512, 256, 0, stream>>>(VVb, VVt, 576);

  // 4) fused bidirectional attention (xv -> vb alias, xl -> LVb alias)
  attn_fused<<<512, 512, 0, stream>>>(Qb, Kb, LVt, VVt, mask, vb, LVb);

  // 5) output GEMMs (f32 out)
  gemm_bt<<<144 * 8, 256, 0, stream>>>(vb,  wvo, bvo, nullptr, out_xv, 18432, 1024, 1024, 8);
  gemm_bt<<<32 * 6,  256, 0, stream>>>(LVb, wlo, blo, nullptr, out_xl, 4096,  768,  1024, 6);
}

// Round 2
// 423.939 us; speedup vs baseline: 1.1709x; 1.1709x over previous
//
#include <hip/hip_runtime.h>
#include <stdint.h>

// BiMultiHeadAttention (GLIP bi-attention), MI355X bf16 MFMA pipeline.
// B=32 VN=576 LN=128 E=1024 H=16 D=64, V_DIM=1024 L_DIM=768, SCALE=0.25.

typedef unsigned short bfu;   // bf16 storage
typedef __attribute__((ext_vector_type(4))) float f32x4;
typedef __attribute__((ext_vector_type(8))) short short8;
typedef __attribute__((ext_vector_type(4))) unsigned short u16x4;

#define MFMA16(a,b,c) __builtin_amdgcn_mfma_f32_16x16x32_bf16((a),(b),(c),0,0,0)
#define SCALE_QK 0.25f

__device__ __forceinline__ unsigned short f2bf(float x) {
  unsigned int u = __float_as_uint(x);
  u += 0x7fffu + ((u >> 16) & 1u);   // round-to-nearest-even
  return (unsigned short)(u >> 16);
}

__device__ __forceinline__ void gload_lds16(const void* g, void* l) {
  __builtin_amdgcn_global_load_lds(
      reinterpret_cast<__attribute__((address_space(1))) void*>(
          reinterpret_cast<uintptr_t>(g)),
      reinterpret_cast<__attribute__((address_space(3))) void*>(
          (uint32_t)reinterpret_cast<uintptr_t>(l)),
      16, 0, 0);
}

// ---------------------------------------------------------------- converts
__global__ void cvt_f32_bf16(const float* __restrict__ x, bfu* __restrict__ y, int n4) {
  for (int i = blockIdx.x * blockDim.x + threadIdx.x; i < n4; i += gridDim.x * blockDim.x) {
    const float4 f = *reinterpret_cast<const float4*>(x + (size_t)i * 4);
    u16x4 o;
    o[0] = f2bf(f.x); o[1] = f2bf(f.y); o[2] = f2bf(f.z); o[3] = f2bf(f.w);
    *reinterpret_cast<u16x4*>(y + (size_t)i * 4) = o;
  }
}

struct CvtArgs {
  const float* src[7];
  bfu* dst[7];
  int n4[7];
};

__global__ void cvt_multi(CvtArgs a) {
  const int s = blockIdx.y;
  const float* __restrict__ x = a.src[s];
  bfu* __restrict__ y = a.dst[s];
  const int n4 = a.n4[s];
  for (int i = blockIdx.x * blockDim.x + threadIdx.x; i < n4; i += gridDim.x * blockDim.x) {
    const float4 f = *reinterpret_cast<const float4*>(x + (size_t)i * 4);
    u16x4 o;
    o[0] = f2bf(f.x); o[1] = f2bf(f.y); o[2] = f2bf(f.z); o[3] = f2bf(f.w);
    *reinterpret_cast<u16x4*>(y + (size_t)i * 4) = o;
  }
}

// ---------------------------------------------------------------- GEMM (C = A @ W^T + bias), m97 structure
// A: M x K bf16 row-major; W: N x K bf16 row-major. M%128==0, N%128==0, K%32==0.
// Output modes: Ct!=null -> transposed bf16 [ (b*16+h)*64+d ][ R ] (col=(h,d), row=(b,q));
//               Cf!=null -> f32 row-major; else Cb bf16 row-major.
__global__ __launch_bounds__(256) void gemm_bt(
    const bfu* __restrict__ A, const bfu* __restrict__ W, const float* __restrict__ bias,
    bfu* __restrict__ Cb, float* __restrict__ Cf, bfu* __restrict__ Ct, int R,
    int M, int N, int K, int nbn)
{
  __shared__ bfu As[128 * 32];
  __shared__ bfu Bs[128 * 32];
  const int nbm = M >> 7;
  const int bid = blockIdx.x;
  int bm, bn;
  if ((nbm & 7) == 0) {             // bijective XCD-aware swizzle: same-XCD blocks share W panel + contiguous bm
    const int xcd = bid & 7, j = bid >> 3;
    const int jm = j / nbn;
    bm = xcd * (nbm >> 3) + jm;
    bn = j - jm * nbn;
  } else { bm = bid / nbn; bn = bid - (bid / nbn) * nbn; }

  const int t = threadIdx.x, l = t & 63, w = t >> 6;
  const int g = l >> 4, c = l & 15;
  const int wr = (w >> 1) * 64, wc = (w & 1) * 64;

  f32x4 zero = {0.f, 0.f, 0.f, 0.f};
  f32x4 acc[4][4];
  for (int m = 0; m < 4; ++m)
    for (int n = 0; n < 4; ++n) acc[m][n] = zero;

  const int rowA = l >> 2;          // 0..15 within 16-row chunk
  const int kb   = (l & 3) * 16;    // byte offset within 64B row

  for (int k0 = 0; k0 < K; k0 += 32) {
#pragma unroll
    for (int i = 0; i < 2; ++i) {
      int chunk = w * 2 + i;
      int r = chunk * 16 + rowA;
      const char* ga = (const char*)(A + (size_t)(bm * 128 + r) * K + k0) + kb;
      const char* gb = (const char*)(W + (size_t)(bn * 128 + r) * K + k0) + kb;
      gload_lds16(ga, (char*)As + chunk * 1024);
      gload_lds16(gb, (char*)Bs + chunk * 1024);
    }
    __syncthreads();
    short8 a[4], bf[4];
#pragma unroll
    for (int m = 0; m < 4; ++m)
      a[m] = *reinterpret_cast<const short8*>(&As[(wr + m * 16 + c) * 32 + g * 8]);
#pragma unroll
    for (int n = 0; n < 4; ++n)
      bf[n] = *reinterpret_cast<const short8*>(&Bs[(wc + n * 16 + c) * 32 + g * 8]);
#pragma unroll
    for (int m = 0; m < 4; ++m)
#pragma unroll
      for (int n = 0; n < 4; ++n)
        acc[m][n] = MFMA16(a[m], bf[n], acc[m][n]);
    __syncthreads();
  }

#pragma unroll
  for (int n = 0; n < 4; ++n) {
    const int col = bn * 128 + wc + n * 16 + c;
    const float bs = bias[col];
    if (Ct) {
      const int hh = col >> 6, dd = col & 63;
#pragma unroll
      for (int m = 0; m < 4; ++m) {
        const int row0 = bm * 128 + wr + m * 16 + g * 4;
        const int bb = row0 / R, q0 = row0 - bb * R;
        u16x4 pk;
#pragma unroll
        for (int r = 0; r < 4; ++r) pk[r] = f2bf(acc[m][n][r] + bs);
        *reinterpret_cast<u16x4*>(Ct + ((size_t)(bb * 16 + hh) * 64 + dd) * R + q0) = pk;
      }
    } else {
#pragma unroll
      for (int m = 0; m < 4; ++m) {
        const int row0 = bm * 128 + wr + m * 16 + g * 4;
#pragma unroll
        for (int r = 0; r < 4; ++r) {
          float val = acc[m][n][r] + bs;
          size_t idx = (size_t)(row0 + r) * N + col;
          if (Cf) Cf[idx] = val;
          else    Cb[idx] = f2bf(val);
        }
      }
    }
  }
}

// ---------------------------------------------------------------- swizzled per-wave P-tile offsets
__device__ __forceinline__ int pvt_off(int q, int kbyte) { return q * 256 + (kbyte ^ ((q & 7) << 4)); }
__device__ __forceinline__ int plt_off(int k, int qbyte) { return k * 64  + (qbyte ^ ((k & 3) << 4)); }

// ---------------------------------------------------------------- attention stage A: xv + P^T + colsum partials
// grid: qc*512 + bh (4608 blocks), 256 threads (4 waves, one 16-row qtile each).
__global__ __launch_bounds__(256) void attn_xv(
    const bfu* __restrict__ Q, const bfu* __restrict__ Kl,
    const bfu* __restrict__ LVt, const float* __restrict__ mask,
    bfu* __restrict__ xv, bfu* __restrict__ PT, float* __restrict__ colpart)
{
  __shared__ short PvT[4][2048];      // per-wave 16x128 bf16 P tile, swizzled
  __shared__ float cp[4][128];

  const int blk = blockIdx.x;
  const int bh = blk & 511, qc = blk >> 9;   // same-bh blocks stride 512 -> same XCD
  const int b = bh >> 4, h = bh & 15;
  const int t = threadIdx.x, l = t & 63, w = t >> 6;
  const int g = l >> 4, c = l & 15;
  const int qt = qc * 4 + w;                 // global qtile 0..35

  const bfu* Qb   = Q   + ((size_t)b * 576 * 1024 + h * 64);
  const bfu* Kb   = Kl  + ((size_t)b * 128 * 1024 + h * 64);
  const bfu* LVtb = LVt + (size_t)bh * 64 * 128;
  const f32x4 zero = {0.f, 0.f, 0.f, 0.f};

  float mk[8];
#pragma unroll
  for (int kt = 0; kt < 8; ++kt) mk[kt] = mask[kt * 16 + c];

  // S = Q K^T for this 16q x 128k tile
  f32x4 sacc[8];
#pragma unroll
  for (int kt = 0; kt < 8; ++kt) sacc[kt] = zero;
#pragma unroll
  for (int kk = 0; kk < 2; ++kk) {
    short8 aq = *reinterpret_cast<const short8*>(Qb + (size_t)(qt * 16 + c) * 1024 + kk * 32 + g * 8);
#pragma unroll
    for (int kt = 0; kt < 8; ++kt) {
      short8 bk = *reinterpret_cast<const short8*>(Kb + (size_t)(kt * 16 + c) * 1024 + kk * 32 + g * 8);
      sacc[kt] = MFMA16(aq, bk, sacc[kt]);
    }
  }

  // P = exp(S*scale + mask[k]); note softmax-over-q is invariant to the per-k mask shift,
  // so this single P serves both softmaxes.
  char* myPv = (char*)&PvT[w][0];
  float rs[4] = {0, 0, 0, 0};
  float colacc[8];
#pragma unroll
  for (int kt = 0; kt < 8; ++kt) {
    u16x4 pk;
    float ca = 0.f;
#pragma unroll
    for (int r = 0; r < 4; ++r) {
      float Ev = __expf(fmaf(sacc[kt][r], SCALE_QK, mk[kt]));
      rs[r] += Ev;
      ca += Ev;
      pk[r] = f2bf(Ev);
      *reinterpret_cast<unsigned short*>(myPv + pvt_off(g * 4 + r, 2 * (kt * 16 + c))) = pk[r];
    }
    colacc[kt] = ca;
    // P^T store: rows k, cols q (contiguous 4 q per lane)
    *reinterpret_cast<u16x4*>(PT + ((size_t)bh * 128 + kt * 16 + c) * 576 + qt * 16 + g * 4) = pk;
  }
  // row-sums over the 16 k-lanes per ktile already partial; reduce across c lanes
#pragma unroll
  for (int r = 0; r < 4; ++r) {
    rs[r] += __shfl_xor(rs[r], 1);
    rs[r] += __shfl_xor(rs[r], 2);
    rs[r] += __shfl_xor(rs[r], 4);
    rs[r] += __shfl_xor(rs[r], 8);
  }

  // xv tile = P(16x128) @ LV(128x64)
  short8 av[4];
#pragma unroll
  for (int kc = 0; kc < 4; ++kc)
    av[kc] = *reinterpret_cast<const short8*>(myPv + pvt_off(c, kc * 64 + g * 16));
  f32x4 oxv[4];
#pragma unroll
  for (int dt = 0; dt < 4; ++dt) oxv[dt] = zero;
#pragma unroll
  for (int dt = 0; dt < 4; ++dt)
#pragma unroll
    for (int kc = 0; kc < 4; ++kc) {
      short8 bv = *reinterpret_cast<const short8*>(LVtb + (size_t)(dt * 16 + c) * 128 + kc * 32 + g * 8);
      oxv[dt] = MFMA16(av[kc], bv, oxv[dt]);
    }
#pragma unroll
  for (int r = 0; r < 4; ++r) rs[r] = 1.0f / rs[r];
#pragma unroll
  for (int dt = 0; dt < 4; ++dt)
#pragma unroll
    for (int r = 0; r < 4; ++r) {
      float val = oxv[dt][r] * rs[r];
      xv[(size_t)(b * 576 + qt * 16 + g * 4 + r) * 1024 + h * 64 + dt * 16 + c] = f2bf(val);
    }

  // column-sum partial for this 64-q block (deterministic, no atomics)
#pragma unroll
  for (int kt = 0; kt < 8; ++kt) {
    colacc[kt] += __shfl_xor(colacc[kt], 16);
    colacc[kt] += __shfl_xor(colacc[kt], 32);
  }
  if (g == 0) {
#pragma unroll
    for (int kt = 0; kt < 8; ++kt) cp[w][kt * 16 + c] = colacc[kt];
  }
  __syncthreads();
  if (t < 128)
    colpart[(size_t)(bh * 9 + qc) * 128 + t] = cp[0][t] + cp[1][t] + cp[2][t] + cp[3][t];
}

// ---------------------------------------------------------------- attention stage B: xl = P^T @ VV / colsum
// grid: kh*512 + bh (1024 blocks), 256 threads (4 waves, one 16-row ktile each).
__global__ __launch_bounds__(256) void attn_xl(
    const bfu* __restrict__ PT, const bfu* __restrict__ VVt,
    const float* __restrict__ colpart, bfu* __restrict__ xl)
{
  const int blk = blockIdx.x;
  const int bh = blk & 511, kh = blk >> 9;   // the 2 blocks sharing VVt land on the same XCD
  const int b = bh >> 4, h = bh & 15;
  const int t = threadIdx.x, l = t & 63, w = t >> 6;
  const int g = l >> 4, c = l & 15;
  const int kt = kh * 4 + w;                 // ktile 0..7

  const bfu* PTb  = PT  + ((size_t)bh * 128 + kt * 16 + c) * 576;
  const bfu* VVtb = VVt + (size_t)bh * 64 * 576;
  const f32x4 zero = {0.f, 0.f, 0.f, 0.f};

  // colsum inverse for this wave's 16 k rows (lane needs rows g*4+r)
  float ci[4];
#pragma unroll
  for (int r = 0; r < 4; ++r) {
    int k = kt * 16 + g * 4 + r;
    float s = 0.f;
#pragma unroll
    for (int qc = 0; qc < 9; ++qc) s += colpart[(size_t)(bh * 9 + qc) * 128 + k];
    ci[r] = 1.0f / s;
  }

  f32x4 acc[4];
#pragma unroll
  for (int dt = 0; dt < 4; ++dt) acc[dt] = zero;

  for (int p = 0; p < 18; ++p) {
    short8 ap = *reinterpret_cast<const short8*>(PTb + p * 32 + g * 8);
#pragma unroll
    for (int dt = 0; dt < 4; ++dt) {
      short8 bv = *reinterpret_cast<const short8*>(VVtb + (size_t)(dt * 16 + c) * 576 + p * 32 + g * 8);
      acc[dt] = MFMA16(ap, bv, acc[dt]);
    }
  }

#pragma unroll
  for (int dt = 0; dt < 4; ++dt)
#pragma unroll
    for (int r = 0; r < 4; ++r) {
      float val = acc[dt][r] * ci[r];
      xl[(size_t)(b * 128 + kt * 16 + g * 4 + r) * 1024 + h * 64 + dt * 16 + c] = f2bf(val);
    }
}

// ---------------------------------------------------------------- fallback: old single-kernel fused attention
__global__ __launch_bounds__(512) void attn_fused(
    const bfu* __restrict__ Q, const bfu* __restrict__ Kl,
    const bfu* __restrict__ LVt, const bfu* __restrict__ VVt,
    const float* __restrict__ mask,
    bfu* __restrict__ xv, bfu* __restrict__ xl)
{
  __shared__ short PvT[8][2048];
  __shared__ short PlT[8][512];
  __shared__ float colpart[8][128];
  __shared__ float colinv[128];

  const int bh = blockIdx.x;
  const int b = bh >> 4, h = bh & 15;
  const int t = threadIdx.x, l = t & 63, w = t >> 6;
  const int g = l >> 4, c = l & 15;

  const bfu* Qb   = Q   + ((size_t)b * 576 * 1024 + h * 64);
  const bfu* Kb   = Kl  + ((size_t)b * 128 * 1024 + h * 64);
  const bfu* LVtb = LVt + (size_t)bh * 64 * 128;
  const bfu* VVtb = VVt + (size_t)bh * 64 * 576;

  const f32x4 zero = {0.f, 0.f, 0.f, 0.f};

  float em[8];
#pragma unroll
  for (int kt = 0; kt < 8; ++kt) em[kt] = __expf(mask[kt * 16 + c]);

  float colacc[8] = {0, 0, 0, 0, 0, 0, 0, 0};
  char* myPv = (char*)&PvT[w][0];

  const int qt0 = (w < 4) ? w * 5 : 20 + (w - 4) * 4;
  const int nqt = (w < 4) ? 5 : 4;

  for (int iq = 0; iq < nqt; ++iq) {
    const int qt = qt0 + iq;
    f32x4 sacc[8];
#pragma unroll
    for (int kt = 0; kt < 8; ++kt) sacc[kt] = zero;
#pragma unroll
    for (int kk = 0; kk < 2; ++kk) {
      short8 aq = *reinterpret_cast<const short8*>(Qb + (size_t)(qt * 16 + c) * 1024 + kk * 32 + g * 8);
#pragma unroll
      for (int kt = 0; kt < 8; ++kt) {
        short8 bk = *reinterpret_cast<const short8*>(Kb + (size_t)(kt * 16 + c) * 1024 + kk * 32 + g * 8);
        sacc[kt] = MFMA16(aq, bk, sacc[kt]);
      }
    }
    float rs[4] = {0, 0, 0, 0};
#pragma unroll
    for (int kt = 0; kt < 8; ++kt) {
#pragma unroll
      for (int r = 0; r < 4; ++r) {
        float El = __expf(sacc[kt][r] * SCALE_QK);
        float Ev = El * em[kt];
        rs[r] += Ev;
        colacc[kt] += El;
        *reinterpret_cast<unsigned short*>(myPv + pvt_off(g * 4 + r, 2 * (kt * 16 + c))) = f2bf(Ev);
      }
    }
#pragma unroll
    for (int r = 0; r < 4; ++r) {
      rs[r] += __shfl_xor(rs[r], 1);
      rs[r] += __shfl_xor(rs[r], 2);
      rs[r] += __shfl_xor(rs[r], 4);
      rs[r] += __shfl_xor(rs[r], 8);
    }
    short8 av[4];
#pragma unroll
    for (int kc = 0; kc < 4; ++kc)
      av[kc] = *reinterpret_cast<const short8*>(myPv + pvt_off(c, kc * 64 + g * 16));
    f32x4 oxv[4];
#pragma unroll
    for (int dt = 0; dt < 4; ++dt) oxv[dt] = zero;
#pragma unroll
    for (int dt = 0; dt < 4; ++dt)
#pragma unroll
      for (int kc = 0; kc < 4; ++kc) {
        short8 bv = *reinterpret_cast<const short8*>(LVtb + (size_t)(dt * 16 + c) * 128 + kc * 32 + g * 8);
        oxv[dt] = MFMA16(av[kc], bv, oxv[dt]);
      }
#pragma unroll
    for (int r = 0; r < 4; ++r) rs[r] = 1.0f / rs[r];
#pragma unroll
    for (int dt = 0; dt < 4; ++dt)
#pragma unroll
      for (int r = 0; r < 4; ++r) {
        float val = oxv[dt][r] * rs[r];
        xv[(size_t)(b * 576 + qt * 16 + g * 4 + r) * 1024 + h * 64 + dt * 16 + c] = f2bf(val);
      }
  }
#pragma unroll
  for (int kt = 0; kt < 8; ++kt) {
    colacc[kt] += __shfl_xor(colacc[kt], 16);
    colacc[kt] += __shfl_xor(colacc[kt], 32);
  }
  if (g == 0) {
#pragma unroll
    for (int kt = 0; kt < 8; ++kt) colpart[w][kt * 16 + c] = colacc[kt];
  }
  __syncthreads();
  if (t < 128) {
    float s = 0.f;
#pragma unroll
    for (int ww = 0; ww < 8; ++ww) s += colpart[ww][t];
    colinv[t] = 1.0f / s;
  }
  __syncthreads();

  short8 bkk[2];
#pragma unroll
  for (int kk = 0; kk < 2; ++kk)
    bkk[kk] = *reinterpret_cast<const short8*>(Kb + (size_t)(w * 16 + c) * 1024 + kk * 32 + g * 8);
  char* myPl = (char*)&PlT[w][0];
  f32x4 oxl[4];
#pragma unroll
  for (int dt = 0; dt < 4; ++dt) oxl[dt] = zero;

  for (int p = 0; p < 18; ++p) {
    f32x4 s0 = zero, s1 = zero;
#pragma unroll
    for (int kk = 0; kk < 2; ++kk) {
      short8 a0 = *reinterpret_cast<const short8*>(Qb + (size_t)((2 * p) * 16 + c) * 1024 + kk * 32 + g * 8);
      short8 a1 = *reinterpret_cast<const short8*>(Qb + (size_t)((2 * p + 1) * 16 + c) * 1024 + kk * 32 + g * 8);
      s0 = MFMA16(a0, bkk[kk], s0);
      s1 = MFMA16(a1, bkk[kk], s1);
    }
#pragma unroll
    for (int half = 0; half < 2; ++half) {
      f32x4 s = half ? s1 : s0;
      unsigned int w0 = (unsigned int)f2bf(__expf(s[0] * SCALE_QK)) |
                        ((unsigned int)f2bf(__expf(s[1] * SCALE_QK)) << 16);
      unsigned int w1 = (unsigned int)f2bf(__expf(s[2] * SCALE_QK)) |
                        ((unsigned int)f2bf(__expf(s[3] * SCALE_QK)) << 16);
      int qb = half * 32 + g * 8;
      *reinterpret_cast<unsigned int*>(myPl + plt_off(c, qb))     = w0;
      *reinterpret_cast<unsigned int*>(myPl + plt_off(c, qb + 4)) = w1;
    }
    short8 apl = *reinterpret_cast<const short8*>(myPl + plt_off(c, g * 16));
#pragma unroll
    for (int dt = 0; dt < 4; ++dt) {
      short8 bv = *reinterpret_cast<const short8*>(VVtb + (size_t)(dt * 16 + c) * 576 + p * 32 + g * 8);
      oxl[dt] = MFMA16(apl, bv, oxl[dt]);
    }
  }
  float ciw[4];
#pragma unroll
  for (int r = 0; r < 4; ++r) ciw[r] = colinv[w * 16 + g * 4 + r];
#pragma unroll
  for (int dt = 0; dt < 4; ++dt)
#pragma unroll
    for (int r = 0; r < 4; ++r) {
      float val = oxl[dt][r] * ciw[r];
      xl[(size_t)(b * 128 + w * 16 + g * 4 + r) * 1024 + h * 64 + dt * 16 + c] = f2bf(val);
    }
}

// ---------------------------------------------------------------- host
static inline int cvt_grid(int n4) {
  int g = (n4 + 255) / 256;
  return g > 4096 ? 4096 : g;
}

extern "C" void kernel_launch(void* const* d_in, const int* in_sizes, int n_in,
                              void* d_out, int out_size, void* d_ws, size_t ws_size,
                              hipStream_t stream)
{
  const float* v    = (const float*)d_in[0];
  const float* lx   = (const float*)d_in[1];
  const float* mask = (const float*)d_in[2];
  const float* Wvq  = (const float*)d_in[3];
  const float* bvq  = (const float*)d_in[4];
  const float* Wlk  = (const float*)d_in[5];
  const float* blk  = (const float*)d_in[6];
  const float* Wvv  = (const float*)d_in[7];
  const float* bvv  = (const float*)d_in[8];
  const float* Wlv  = (const float*)d_in[9];
  const float* blv  = (const float*)d_in[10];
  const float* Wvo  = (const float*)d_in[11];
  const float* bvo  = (const float*)d_in[12];
  const float* Wlo  = (const float*)d_in[13];
  const float* blo  = (const float*)d_in[14];

  float* out_xv = (float*)d_out;                       // 18432 x 1024
  float* out_xl = out_xv + (size_t)18432 * 1024;       // 4096 x 768

  bfu* ws  = (bfu*)d_ws;
  bfu* vb  = ws;                      // 18874368 (later aliased as xv bf16)
  bfu* lb  = vb  + 18874368;          // 3145728
  bfu* wq  = lb  + 3145728;           // 1048576
  bfu* wk  = wq  + 1048576;           // 786432
  bfu* wv  = wk  + 786432;            // 1048576
  bfu* wlv = wv  + 1048576;           // 786432
  bfu* wvo = wlv + 786432;            // 1048576
  bfu* wlo = wvo + 1048576;           // 786432
  bfu* Qb  = wlo + 786432;            // 18874368
  bfu* VVt = Qb  + 18874368;          // 18874368  [bh][64][576]
  bfu* Kb  = VVt + 18874368;          // 4194304  (later aliased as xl bf16)
  bfu* LVt = Kb  + 4194304;           // 4194304  [bh][64][128]
  bfu* PT  = LVt + 4194304;           // 37748736 [bh][128][576]
  float* colpart = (float*)(PT + 37748736);            // 512*9*128 f32
  const size_t need = (size_t)((char*)(colpart + 512 * 9 * 128) - (char*)d_ws);
  const bool split = ws_size >= need;

  // 1) converts
  cvt_f32_bf16<<<cvt_grid(18874368 / 4), 256, 0, stream>>>(v, vb, 18874368 / 4);
  CvtArgs ca;
  ca.src[0] = lx;  ca.dst[0] = lb;  ca.n4[0] = 3145728 / 4;
  ca.src[1] = Wvq; ca.dst[1] = wq;  ca.n4[1] = 1048576 / 4;
  ca.src[2] = Wlk; ca.dst[2] = wk;  ca.n4[2] = 786432 / 4;
  ca.src[3] = Wvv; ca.dst[3] = wv;  ca.n4[3] = 1048576 / 4;
  ca.src[4] = Wlv; ca.dst[4] = wlv; ca.n4[4] = 786432 / 4;
  ca.src[5] = Wvo; ca.dst[5] = wvo; ca.n4[5] = 1048576 / 4;
  ca.src[6] = Wlo; ca.dst[6] = wlo; ca.n4[6] = 786432 / 4;
  cvt_multi<<<dim3(1024, 7), 256, 0, stream>>>(ca);

  // 2) projection GEMMs (VV/LV written directly transposed -> no transpose kernels)
  gemm_bt<<<144 * 8, 256, 0, stream>>>(vb, wq,  bvq, Qb, nullptr, nullptr, 0, 18432, 1024, 1024, 8);
  gemm_bt<<<144 * 8, 256, 0, stream>>>(vb, wv,  bvv, nullptr, nullptr, VVt, 576, 18432, 1024, 1024, 8);
  gemm_bt<<<32 * 8,  256, 0, stream>>>(lb, wk,  blk, Kb, nullptr, nullptr, 0, 4096, 1024, 768, 8);
  gemm_bt<<<32 * 8,  256, 0, stream>>>(lb, wlv, blv, nullptr, nullptr, LVt, 128, 4096, 1024, 768, 8);

  // 3) attention (xv -> vb alias, xl -> Kb alias)
  if (split) {
    attn_xv<<<512 * 9, 256, 0, stream>>>(Qb, Kb, LVt, mask, vb, PT, colpart);
    attn_xl<<<512 * 2, 256, 0, stream>>>(PT, VVt, colpart, Kb);
  } else {
    attn_fused<<<512, 512, 0, stream>>>(Qb, Kb, LVt, VVt, mask, vb, Kb);
  }

  // 4) output GEMMs (f32 out)
  gemm_bt<<<144 * 8, 256, 0, stream>>>(vb, wvo, bvo, nullptr, out_xv, nullptr, 0, 18432, 1024, 1024, 8);
  gemm_bt<<<32 * 6,  256, 0, stream>>>(Kb, wlo, blo, nullptr, out_xl, nullptr, 0, 4096, 768, 1024, 6);
}